// Round 8
// baseline (693.181 us; speedup 1.0000x reference)
//
#include <hip/hip_runtime.h>
#include <hip/hip_bf16.h>

#define NN 8192
#define NE 262144

typedef __attribute__((ext_vector_type(8))) short bf16x8;
typedef __attribute__((ext_vector_type(4))) float f32x4;

// ---------------- CSR build ----------------
__global__ __launch_bounds__(256) void k_count(const int* __restrict__ ei, const float* __restrict__ w,
                                               float* __restrict__ deg, int* __restrict__ counts) {
  int e = blockIdx.x * 256 + threadIdx.x;
  if (e < NE) {
    int c = ei[NE + e];
    atomicAdd(&deg[c], w[e]);
    atomicAdd(&counts[c], 1);
  }
}

__global__ __launch_bounds__(1024) void k_scan(const int* __restrict__ counts, int* __restrict__ offs) {
  __shared__ int part[1024];
  int t = threadIdx.x;
  int base = t * 8;
  int local[8];
  int s = 0;
#pragma unroll
  for (int j = 0; j < 8; ++j) { local[j] = counts[base + j]; s += local[j]; }
  part[t] = s;
  __syncthreads();
  for (int off = 1; off < 1024; off <<= 1) {
    int v = (t >= off) ? part[t - off] : 0;
    __syncthreads();
    part[t] += v;
    __syncthreads();
  }
  int run = (t > 0) ? part[t - 1] : 0;
#pragma unroll
  for (int j = 0; j < 8; ++j) { offs[base + j] = run; run += local[j]; }
  if (t == 1023) offs[NN] = run;
}

__global__ __launch_bounds__(256) void k_scatter(const int* __restrict__ ei, const float* __restrict__ w,
                                                 const float* __restrict__ deg, const int* __restrict__ offs,
                                                 int* __restrict__ cnt2, int* __restrict__ csr_row,
                                                 float* __restrict__ csr_val) {
  int e = blockIdx.x * 256 + threadIdx.x;
  if (e < NE) {
    int r = ei[e], c = ei[NE + e];
    int slot = offs[c] + atomicAdd(&cnt2[c], 1);
    csr_row[slot] = r;
    csr_val[slot] = rsqrtf(deg[r]) * w[e] * rsqrtf(deg[c]);
  }
}

// ---------------- split x (+ absorbs CSR init) ----------------
__global__ __launch_bounds__(256) void k_splitX(const float* __restrict__ x,
                                                __hip_bfloat16* __restrict__ xh,
                                                __hip_bfloat16* __restrict__ xl,
                                                float* __restrict__ deg, int* __restrict__ counts,
                                                int* __restrict__ cnt2) {
  int gtid = blockIdx.x * 256 + threadIdx.x;
  if (gtid < NN) { deg[gtid] = 1.0f; counts[gtid] = 0; cnt2[gtid] = 0; }
  size_t i = (size_t)gtid * 4;
  f32x4 v = *(const f32x4*)(x + i);
#pragma unroll
  for (int j = 0; j < 4; ++j) {
    __hip_bfloat16 h = __float2bfloat16(v[j]);
    xh[i + j] = h;
    xl[i + j] = __float2bfloat16(v[j] - __bfloat162float(h));
  }
}

// ---------------- one kernel: split+transpose all weights, build bcat ----------------
__global__ __launch_bounds__(256) void k_prep(const float* __restrict__ W1, const float* __restrict__ W2,
                                              const float* __restrict__ Wm, const float* __restrict__ Wsw,
                                              const float* __restrict__ bm, const float* __restrict__ bsv,
                                              __hip_bfloat16* __restrict__ W1hT, __hip_bfloat16* __restrict__ W1lT,
                                              __hip_bfloat16* __restrict__ W2hT, __hip_bfloat16* __restrict__ W2lT,
                                              __hip_bfloat16* __restrict__ WchT, __hip_bfloat16* __restrict__ WclT,
                                              float* __restrict__ bcat) {
  int gtid = blockIdx.x * 256 + threadIdx.x;
  int gs = gridDim.x * 256;
  for (int idx = gtid; idx < 512 * 256; idx += gs) {
    int k = idx >> 8, n = idx & 255;
    float v = W1[idx];
    __hip_bfloat16 h = __float2bfloat16(v);
    W1hT[n * 512 + k] = h;
    W1lT[n * 512 + k] = __float2bfloat16(v - __bfloat162float(h));
  }
  for (int idx = gtid; idx < 256 * 256; idx += gs) {
    int k = idx >> 8, n = idx & 255;
    float v = W2[idx];
    __hip_bfloat16 h = __float2bfloat16(v);
    W2hT[n * 256 + k] = h;
    W2lT[n * 256 + k] = __float2bfloat16(v - __bfloat162float(h));
  }
  for (int idx = gtid; idx < 128 * 256; idx += gs) {
    int n = idx >> 8, k = idx & 255;
    float v = (n < 64) ? Wm[k * 64 + n] : Wsw[k * 64 + (n - 64)];
    __hip_bfloat16 h = __float2bfloat16(v);
    WchT[idx] = h;
    WclT[idx] = __float2bfloat16(v - __bfloat162float(h));
  }
  if (gtid < 128) bcat[gtid] = (gtid < 64) ? bm[gtid] : bsv[gtid - 64];
}

// ---------------- split-bf16 MFMA GEMM, compile-time K/Nc; REP amplification for profiling ----------------
template <int K, int Nc, int REP>
__global__ __launch_bounds__(256) void k_gemm_mfma(const short* __restrict__ Ah, const short* __restrict__ Al,
                                                   const short* __restrict__ BhT, const short* __restrict__ BlT,
                                                   float* __restrict__ C) {
  int m0 = blockIdx.y * 64, n0 = blockIdx.x * 64;
  int wv = threadIdx.x >> 6, lane = threadIdx.x & 63;
  int wr = wv >> 1, wc = wv & 1;
  int lr = lane & 15, lk8 = (lane >> 4) << 3;
  int arow = m0 + wr * 32 + lr;
  int bcol = n0 + wc * 32 + lr;
  for (int rep = 0; rep < REP; ++rep) {
    asm volatile("" ::: "memory");   // keep loads+MFMA inside the rep loop (no hoisting)
    f32x4 acc[2][2] = {};
#pragma unroll 4
    for (int k0 = 0; k0 < K; k0 += 32) {
      bf16x8 ah[2], al[2], bh[2], bl[2];
#pragma unroll
      for (int rb = 0; rb < 2; ++rb) {
        size_t o = (size_t)(arow + rb * 16) * K + k0 + lk8;
        ah[rb] = *(const bf16x8*)(Ah + o);
        al[rb] = *(const bf16x8*)(Al + o);
      }
#pragma unroll
      for (int cb = 0; cb < 2; ++cb) {
        size_t o = (size_t)(bcol + cb * 16) * K + k0 + lk8;
        bh[cb] = *(const bf16x8*)(BhT + o);
        bl[cb] = *(const bf16x8*)(BlT + o);
      }
#pragma unroll
      for (int rb = 0; rb < 2; ++rb)
#pragma unroll
        for (int cb = 0; cb < 2; ++cb) {
          f32x4 c = acc[rb][cb];
          c = __builtin_amdgcn_mfma_f32_16x16x32_bf16(ah[rb], bh[cb], c, 0, 0, 0);
          c = __builtin_amdgcn_mfma_f32_16x16x32_bf16(ah[rb], bl[cb], c, 0, 0, 0);
          c = __builtin_amdgcn_mfma_f32_16x16x32_bf16(al[rb], bh[cb], c, 0, 0, 0);
          acc[rb][cb] = c;
        }
    }
    int orow = m0 + wr * 32 + ((lane >> 4) << 2);
    int ocol = n0 + wc * 32 + (lane & 15);
#pragma unroll
    for (int rb = 0; rb < 2; ++rb)
#pragma unroll
      for (int cb = 0; cb < 2; ++cb)
#pragma unroll
        for (int r = 0; r < 4; ++r)
          C[(size_t)(orow + rb * 16 + r) * Nc + ocol + cb * 16] = acc[rb][cb][r];
  }
}

// ---------------- CSR aggregation; ZMODE=1 fuses reparameterized z (D=128 only) ----------------
template <int D, bool SPLIT, int ZMODE>
__global__ __launch_bounds__(256) void k_agg(const float* __restrict__ t, const float* __restrict__ deg,
                                             const int* __restrict__ csr_row, const float* __restrict__ csr_val,
                                             const int* __restrict__ offs, const float* __restrict__ bias,
                                             const float* __restrict__ noise,
                                             __hip_bfloat16* __restrict__ outh,
                                             __hip_bfloat16* __restrict__ outl) {
  constexpr int V = D / 64;
  __shared__ int   srow[256];
  __shared__ float sval[256];
  __shared__ float sacc[4][D];
  int c = blockIdx.x;
  int tid = threadIdx.x;
  int w = tid >> 6, lane = tid & 63;
  int d0 = lane * V;
  float acc[V];
#pragma unroll
  for (int j = 0; j < V; ++j) acc[j] = 0.0f;
  int s0 = offs[c], s1 = offs[c + 1];
  for (int base = s0; base < s1; base += 256) {
    int cnt = s1 - base; if (cnt > 256) cnt = 256;
    __syncthreads();
    if (tid < cnt) { srow[tid] = csr_row[base + tid]; sval[tid] = csr_val[base + tid]; }
    __syncthreads();
    for (int s = w; s < cnt; s += 4) {
      int r = srow[s];
      float v = sval[s];
      const float* q = t + (size_t)r * D + d0;
      if constexpr (V == 4) {
        float4 pv = *(const float4*)q;
        acc[0] = fmaf(v, pv.x, acc[0]);
        acc[1] = fmaf(v, pv.y, acc[1]);
        acc[2] = fmaf(v, pv.z, acc[2]);
        acc[3] = fmaf(v, pv.w, acc[3]);
      } else {
        float2 pv = *(const float2*)q;
        acc[0] = fmaf(v, pv.x, acc[0]);
        acc[1] = fmaf(v, pv.y, acc[1]);
      }
    }
  }
#pragma unroll
  for (int j = 0; j < V; ++j) sacc[w][d0 + j] = acc[j];
  __syncthreads();
  if (tid < 64) {
    float di = rsqrtf(deg[c]);
    float selfw = di * di;
#pragma unroll
    for (int j = 0; j < V; ++j) {
      int d = tid * V + j;
      float a = sacc[0][d] + sacc[1][d] + sacc[2][d] + sacc[3][d];
      a = fmaf(selfw, t[(size_t)c * D + d], a);
      a = fmaxf(a + bias[d], 0.0f);
      if constexpr (ZMODE == 0) {
        __hip_bfloat16 h = __float2bfloat16(a);
        outh[(size_t)c * D + d] = h;
        outl[(size_t)c * D + d] = __float2bfloat16(a - __bfloat162float(h));
      } else {
        sacc[0][d] = a;    // own d only: no cross-thread hazard before sync
      }
    }
  }
  if constexpr (ZMODE == 1) {
    __syncthreads();
    if (tid < 64) {
      float mean = sacc[0][tid];
      float ls = sacc[0][64 + tid];
      float z = noise[(size_t)c * 64 + tid] * __expf(ls) + mean;
      __hip_bfloat16 h = __float2bfloat16(z);
      outh[(size_t)c * 64 + tid] = h;
      outl[(size_t)c * 64 + tid] = __float2bfloat16(z - __bfloat162float(h));
    }
  }
}

// ---------------- final: triu(sigmoid(z z^T), 1), split-bf16 MFMA ----------------
__global__ __launch_bounds__(256) void k_final(const short* __restrict__ zh, const short* __restrict__ zl,
                                               float* __restrict__ out) {
  int ti = blockIdx.y, tj = blockIdx.x;
  int ri0 = ti * 128, cj0 = tj * 128;
  if (tj < ti) {
    f32x4 zz = {};
    int tr = threadIdx.x >> 5;
    int tc = (threadIdx.x & 31) << 2;
    float* base = out + (size_t)(ri0 + tr) * NN + cj0 + tc;
#pragma unroll
    for (int rr = 0; rr < 128; rr += 8)
      *(f32x4*)(base + (size_t)rr * NN) = zz;
    return;
  }
  int wv = threadIdx.x >> 6;
  int lane = threadIdx.x & 63;
  int wr = wv >> 1, wc = wv & 1;
  int lr = lane & 15;
  int lk = (lane >> 4) << 3;
  int arow = ri0 + wr * 64 + lr;
  int brow = cj0 + wc * 64 + lr;

  bf16x8 ah[4][2], al[4][2];
#pragma unroll
  for (int rb = 0; rb < 4; ++rb)
#pragma unroll
    for (int ks = 0; ks < 2; ++ks) {
      int o = (arow + rb * 16) * 64 + ks * 32 + lk;
      ah[rb][ks] = *(const bf16x8*)(zh + o);
      al[rb][ks] = *(const bf16x8*)(zl + o);
    }
  int orow = ri0 + wr * 64 + ((lane >> 4) << 2);
  int ocol = cj0 + wc * 64 + (lane & 15);
#pragma unroll
  for (int cb = 0; cb < 4; ++cb) {
    bf16x8 bh[2], bl[2];
#pragma unroll
    for (int ks = 0; ks < 2; ++ks) {
      int o = (brow + cb * 16) * 64 + ks * 32 + lk;
      bh[ks] = *(const bf16x8*)(zh + o);
      bl[ks] = *(const bf16x8*)(zl + o);
    }
    f32x4 acc[4] = {};
#pragma unroll
    for (int rb = 0; rb < 4; ++rb) {
      f32x4 c = acc[rb];
#pragma unroll
      for (int ks = 0; ks < 2; ++ks) {
        c = __builtin_amdgcn_mfma_f32_16x16x32_bf16(ah[rb][ks], bh[ks], c, 0, 0, 0);
        c = __builtin_amdgcn_mfma_f32_16x16x32_bf16(ah[rb][ks], bl[ks], c, 0, 0, 0);
        c = __builtin_amdgcn_mfma_f32_16x16x32_bf16(al[rb][ks], bh[ks], c, 0, 0, 0);
      }
      acc[rb] = c;
    }
#pragma unroll
    for (int rb = 0; rb < 4; ++rb)
#pragma unroll
      for (int r = 0; r < 4; ++r) {
        int row = orow + rb * 16 + r;
        int col = ocol + cb * 16;
        float v = acc[rb][r];
        float sg = 1.0f / (1.0f + __expf(-v));
        out[(size_t)row * NN + col] = (col > row) ? sg : 0.0f;
      }
  }
}

extern "C" void kernel_launch(void* const* d_in, const int* in_sizes, int n_in,
                              void* d_out, int out_size, void* d_ws, size_t ws_size,
                              hipStream_t stream) {
  (void)in_sizes; (void)n_in; (void)out_size; (void)ws_size;
  const float* x     = (const float*)d_in[0];
  const int*   ei    = (const int*)d_in[1];
  const float* ew    = (const float*)d_in[2];
  const float* noise = (const float*)d_in[3];
  const float* W1    = (const float*)d_in[4];
  const float* b1    = (const float*)d_in[5];
  const float* W2    = (const float*)d_in[6];
  const float* b2    = (const float*)d_in[7];
  const float* Wm    = (const float*)d_in[8];
  const float* bm    = (const float*)d_in[9];
  const float* Wsw   = (const float*)d_in[10];
  const float* bsv   = (const float*)d_in[11];
  float* out = (float*)d_out;

  char* wsb = (char*)d_ws;
  size_t off = 0;
  auto bump = [&](size_t bytes) -> void* {
    void* p = wsb + off;
    off += (bytes + 255) & ~(size_t)255;
    return p;
  };
  float* deg     = (float*)bump((size_t)NN * 4);
  int*   counts  = (int*)bump((size_t)NN * 4);
  int*   offs    = (int*)bump((size_t)(NN + 1) * 4);
  int*   cnt2    = (int*)bump((size_t)NN * 4);
  int*   csr_row = (int*)bump((size_t)NE * 4);
  float* csr_val = (float*)bump((size_t)NE * 4);
  __hip_bfloat16* xh = (__hip_bfloat16*)bump((size_t)NN * 512 * 2);
  __hip_bfloat16* xl = (__hip_bfloat16*)bump((size_t)NN * 512 * 2);
  float* bufA    = (float*)bump((size_t)NN * 256 * 4);
  __hip_bfloat16* h1h = (__hip_bfloat16*)bump((size_t)NN * 256 * 2);
  __hip_bfloat16* h1l = (__hip_bfloat16*)bump((size_t)NN * 256 * 2);
  __hip_bfloat16* W1hT = (__hip_bfloat16*)bump((size_t)256 * 512 * 2);
  __hip_bfloat16* W1lT = (__hip_bfloat16*)bump((size_t)256 * 512 * 2);
  __hip_bfloat16* W2hT = (__hip_bfloat16*)bump((size_t)256 * 256 * 2);
  __hip_bfloat16* W2lT = (__hip_bfloat16*)bump((size_t)256 * 256 * 2);
  __hip_bfloat16* WchT = (__hip_bfloat16*)bump((size_t)128 * 256 * 2);
  __hip_bfloat16* WclT = (__hip_bfloat16*)bump((size_t)128 * 256 * 2);
  float* bcat    = (float*)bump((size_t)128 * 4);
  __hip_bfloat16* zh = (__hip_bfloat16*)bump((size_t)NN * 64 * 2);
  __hip_bfloat16* zl = (__hip_bfloat16*)bump((size_t)NN * 64 * 2);

  __hip_bfloat16* h2h = xh;                 // alias: x pair dead after GEMM1
  __hip_bfloat16* h2l = xl;

  // CSR build + splits
  k_splitX<<<NN * 512 / 4 / 256, 256, 0, stream>>>(x, xh, xl, deg, counts, cnt2);
  k_count<<<NE / 256, 256, 0, stream>>>(ei, ew, deg, counts);
  k_scan<<<1, 1024, 0, stream>>>(counts, offs);
  k_scatter<<<NE / 256, 256, 0, stream>>>(ei, ew, deg, offs, cnt2, csr_row, csr_val);
  k_prep<<<896, 256, 0, stream>>>(W1, W2, Wm, Wsw, bm, bsv, W1hT, W1lT, W2hT, W2lT, WchT, WclT, bcat);

  // layer 1 (GEMM amplified x16 for rocprof visibility; idempotent)
  k_gemm_mfma<512, 256, 16><<<dim3(4, 128), 256, 0, stream>>>((const short*)xh, (const short*)xl,
                                                              (const short*)W1hT, (const short*)W1lT, bufA);
  k_agg<256, true, 0><<<NN, 256, 0, stream>>>(bufA, deg, csr_row, csr_val, offs, b1, nullptr, h1h, h1l);
  // layer 2
  k_gemm_mfma<256, 256, 1><<<dim3(4, 128), 256, 0, stream>>>((const short*)h1h, (const short*)h1l,
                                                             (const short*)W2hT, (const short*)W2lT, bufA);
  k_agg<256, true, 0><<<NN, 256, 0, stream>>>(bufA, deg, csr_row, csr_val, offs, b2, nullptr, h2h, h2l);
  // heads + fused z
  k_gemm_mfma<256, 128, 1><<<dim3(2, 128), 256, 0, stream>>>((const short*)h2h, (const short*)h2l,
                                                             (const short*)WchT, (const short*)WclT, bufA);
  k_agg<128, false, 1><<<NN, 256, 0, stream>>>(bufA, deg, csr_row, csr_val, offs, bcat, noise, zh, zl);
  // final
  k_final<<<dim3(64, 64), 256, 0, stream>>>((const short*)zh, (const short*)zl, out);
}

// Round 9
// 322.181 us; speedup vs baseline: 2.1515x; 2.1515x over previous
//
#include <hip/hip_runtime.h>
#include <hip/hip_bf16.h>

#define NN 8192
#define NE 262144

typedef __attribute__((ext_vector_type(8))) short bf16x8;
typedef __attribute__((ext_vector_type(4))) float f32x4;

// ---------------- CSR build ----------------
__global__ __launch_bounds__(256) void k_count(const int* __restrict__ ei, const float* __restrict__ w,
                                               float* __restrict__ deg, int* __restrict__ counts) {
  int e = blockIdx.x * 256 + threadIdx.x;
  if (e < NE) {
    int c = ei[NE + e];
    atomicAdd(&deg[c], w[e]);
    atomicAdd(&counts[c], 1);
  }
}

__global__ __launch_bounds__(1024) void k_scan(const int* __restrict__ counts, int* __restrict__ offs) {
  __shared__ int part[1024];
  int t = threadIdx.x;
  int base = t * 8;
  int local[8];
  int s = 0;
#pragma unroll
  for (int j = 0; j < 8; ++j) { local[j] = counts[base + j]; s += local[j]; }
  part[t] = s;
  __syncthreads();
  for (int off = 1; off < 1024; off <<= 1) {
    int v = (t >= off) ? part[t - off] : 0;
    __syncthreads();
    part[t] += v;
    __syncthreads();
  }
  int run = (t > 0) ? part[t - 1] : 0;
#pragma unroll
  for (int j = 0; j < 8; ++j) { offs[base + j] = run; run += local[j]; }
  if (t == 1023) offs[NN] = run;
}

__global__ __launch_bounds__(256) void k_scatter(const int* __restrict__ ei, const float* __restrict__ w,
                                                 const float* __restrict__ deg, const int* __restrict__ offs,
                                                 int* __restrict__ cnt2, int* __restrict__ csr_row,
                                                 float* __restrict__ csr_val) {
  int e = blockIdx.x * 256 + threadIdx.x;
  if (e < NE) {
    int r = ei[e], c = ei[NE + e];
    int slot = offs[c] + atomicAdd(&cnt2[c], 1);
    csr_row[slot] = r;
    csr_val[slot] = rsqrtf(deg[r]) * w[e] * rsqrtf(deg[c]);
  }
}

// ---------------- split x (+ absorbs CSR init) ----------------
__global__ __launch_bounds__(256) void k_splitX(const float* __restrict__ x,
                                                __hip_bfloat16* __restrict__ xh,
                                                __hip_bfloat16* __restrict__ xl,
                                                float* __restrict__ deg, int* __restrict__ counts,
                                                int* __restrict__ cnt2) {
  int gtid = blockIdx.x * 256 + threadIdx.x;
  if (gtid < NN) { deg[gtid] = 1.0f; counts[gtid] = 0; cnt2[gtid] = 0; }
  size_t i = (size_t)gtid * 4;
  f32x4 v = *(const f32x4*)(x + i);
#pragma unroll
  for (int j = 0; j < 4; ++j) {
    __hip_bfloat16 h = __float2bfloat16(v[j]);
    xh[i + j] = h;
    xl[i + j] = __float2bfloat16(v[j] - __bfloat162float(h));
  }
}

// ---------------- one kernel: split+transpose all weights, build bcat ----------------
__global__ __launch_bounds__(256) void k_prep(const float* __restrict__ W1, const float* __restrict__ W2,
                                              const float* __restrict__ Wm, const float* __restrict__ Wsw,
                                              const float* __restrict__ bm, const float* __restrict__ bsv,
                                              __hip_bfloat16* __restrict__ W1hT, __hip_bfloat16* __restrict__ W1lT,
                                              __hip_bfloat16* __restrict__ W2hT, __hip_bfloat16* __restrict__ W2lT,
                                              __hip_bfloat16* __restrict__ WchT, __hip_bfloat16* __restrict__ WclT,
                                              float* __restrict__ bcat) {
  int gtid = blockIdx.x * 256 + threadIdx.x;
  int gs = gridDim.x * 256;
  for (int idx = gtid; idx < 512 * 256; idx += gs) {
    int k = idx >> 8, n = idx & 255;
    float v = W1[idx];
    __hip_bfloat16 h = __float2bfloat16(v);
    W1hT[n * 512 + k] = h;
    W1lT[n * 512 + k] = __float2bfloat16(v - __bfloat162float(h));
  }
  for (int idx = gtid; idx < 256 * 256; idx += gs) {
    int k = idx >> 8, n = idx & 255;
    float v = W2[idx];
    __hip_bfloat16 h = __float2bfloat16(v);
    W2hT[n * 256 + k] = h;
    W2lT[n * 256 + k] = __float2bfloat16(v - __bfloat162float(h));
  }
  for (int idx = gtid; idx < 128 * 256; idx += gs) {
    int n = idx >> 8, k = idx & 255;
    float v = (n < 64) ? Wm[k * 64 + n] : Wsw[k * 64 + (n - 64)];
    __hip_bfloat16 h = __float2bfloat16(v);
    WchT[idx] = h;
    WclT[idx] = __float2bfloat16(v - __bfloat162float(h));
  }
  if (gtid < 128) bcat[gtid] = (gtid < 64) ? bm[gtid] : bsv[gtid - 64];
}

// ---------------- split-bf16 MFMA GEMM: 32x32 blocks, 16x16 wave-tiles (high TLP) ----------------
// grid = (NN/32) * (Nc/32) 1-D; by = b % 256 so the Nc/32 blocks sharing an A-panel
// are congruent mod 8 -> same XCD -> A-panel L2-resident per XCD.
template <int K, int Nc>
__global__ __launch_bounds__(256, 4) void k_gemm_mfma(const short* __restrict__ Ah, const short* __restrict__ Al,
                                                      const short* __restrict__ BhT, const short* __restrict__ BlT,
                                                      float* __restrict__ C) {
  constexpr int NBY = NN / 32;
  int b = blockIdx.x;
  int by = b & (NBY - 1);        // NBY=256, power of 2
  int bx = b >> 8;
  int wv = threadIdx.x >> 6, lane = threadIdx.x & 63;
  int wr = wv >> 1, wc = wv & 1;
  int lr = lane & 15, lk8 = (lane >> 4) << 3;
  int arow = by * 32 + wr * 16 + lr;
  int bcol = bx * 32 + wc * 16 + lr;
  f32x4 acc = {};
#pragma unroll 4
  for (int k0 = 0; k0 < K; k0 += 32) {
    bf16x8 ah = *(const bf16x8*)(Ah + (size_t)arow * K + k0 + lk8);
    bf16x8 al = *(const bf16x8*)(Al + (size_t)arow * K + k0 + lk8);
    bf16x8 bh = *(const bf16x8*)(BhT + (size_t)bcol * K + k0 + lk8);
    bf16x8 bl = *(const bf16x8*)(BlT + (size_t)bcol * K + k0 + lk8);
    acc = __builtin_amdgcn_mfma_f32_16x16x32_bf16(ah, bh, acc, 0, 0, 0);
    acc = __builtin_amdgcn_mfma_f32_16x16x32_bf16(ah, bl, acc, 0, 0, 0);
    acc = __builtin_amdgcn_mfma_f32_16x16x32_bf16(al, bh, acc, 0, 0, 0);
  }
  int orow = by * 32 + wr * 16 + ((lane >> 4) << 2);
  int ocol = bx * 32 + wc * 16 + (lane & 15);
#pragma unroll
  for (int r = 0; r < 4; ++r)
    C[(size_t)(orow + r) * Nc + ocol] = acc[r];
}

// ---------------- CSR aggregation; ZMODE=1 fuses reparameterized z (D=128 only) ----------------
template <int D, bool SPLIT, int ZMODE>
__global__ __launch_bounds__(256) void k_agg(const float* __restrict__ t, const float* __restrict__ deg,
                                             const int* __restrict__ csr_row, const float* __restrict__ csr_val,
                                             const int* __restrict__ offs, const float* __restrict__ bias,
                                             const float* __restrict__ noise,
                                             __hip_bfloat16* __restrict__ outh,
                                             __hip_bfloat16* __restrict__ outl) {
  constexpr int V = D / 64;
  __shared__ int   srow[256];
  __shared__ float sval[256];
  __shared__ float sacc[4][D];
  int c = blockIdx.x;
  int tid = threadIdx.x;
  int w = tid >> 6, lane = tid & 63;
  int d0 = lane * V;
  float acc[V];
#pragma unroll
  for (int j = 0; j < V; ++j) acc[j] = 0.0f;
  int s0 = offs[c], s1 = offs[c + 1];
  for (int base = s0; base < s1; base += 256) {
    int cnt = s1 - base; if (cnt > 256) cnt = 256;
    __syncthreads();
    if (tid < cnt) { srow[tid] = csr_row[base + tid]; sval[tid] = csr_val[base + tid]; }
    __syncthreads();
    for (int s = w; s < cnt; s += 4) {
      int r = srow[s];
      float v = sval[s];
      const float* q = t + (size_t)r * D + d0;
      if constexpr (V == 4) {
        float4 pv = *(const float4*)q;
        acc[0] = fmaf(v, pv.x, acc[0]);
        acc[1] = fmaf(v, pv.y, acc[1]);
        acc[2] = fmaf(v, pv.z, acc[2]);
        acc[3] = fmaf(v, pv.w, acc[3]);
      } else {
        float2 pv = *(const float2*)q;
        acc[0] = fmaf(v, pv.x, acc[0]);
        acc[1] = fmaf(v, pv.y, acc[1]);
      }
    }
  }
#pragma unroll
  for (int j = 0; j < V; ++j) sacc[w][d0 + j] = acc[j];
  __syncthreads();
  if (tid < 64) {
    float di = rsqrtf(deg[c]);
    float selfw = di * di;
#pragma unroll
    for (int j = 0; j < V; ++j) {
      int d = tid * V + j;
      float a = sacc[0][d] + sacc[1][d] + sacc[2][d] + sacc[3][d];
      a = fmaf(selfw, t[(size_t)c * D + d], a);
      a = fmaxf(a + bias[d], 0.0f);
      if constexpr (ZMODE == 0) {
        __hip_bfloat16 h = __float2bfloat16(a);
        outh[(size_t)c * D + d] = h;
        outl[(size_t)c * D + d] = __float2bfloat16(a - __bfloat162float(h));
      } else {
        sacc[0][d] = a;    // own d only: no cross-thread hazard before sync
      }
    }
  }
  if constexpr (ZMODE == 1) {
    __syncthreads();
    if (tid < 64) {
      float mean = sacc[0][tid];
      float ls = sacc[0][64 + tid];
      float z = noise[(size_t)c * 64 + tid] * __expf(ls) + mean;
      __hip_bfloat16 h = __float2bfloat16(z);
      outh[(size_t)c * 64 + tid] = h;
      outl[(size_t)c * 64 + tid] = __float2bfloat16(z - __bfloat162float(h));
    }
  }
}

// ---------------- final: triu(sigmoid(z z^T), 1), split-bf16 MFMA ----------------
__global__ __launch_bounds__(256) void k_final(const short* __restrict__ zh, const short* __restrict__ zl,
                                               float* __restrict__ out) {
  int ti = blockIdx.y, tj = blockIdx.x;
  int ri0 = ti * 128, cj0 = tj * 128;
  if (tj < ti) {
    f32x4 zz = {};
    int tr = threadIdx.x >> 5;
    int tc = (threadIdx.x & 31) << 2;
    float* base = out + (size_t)(ri0 + tr) * NN + cj0 + tc;
#pragma unroll
    for (int rr = 0; rr < 128; rr += 8)
      *(f32x4*)(base + (size_t)rr * NN) = zz;
    return;
  }
  int wv = threadIdx.x >> 6;
  int lane = threadIdx.x & 63;
  int wr = wv >> 1, wc = wv & 1;
  int lr = lane & 15;
  int lk = (lane >> 4) << 3;
  int arow = ri0 + wr * 64 + lr;
  int brow = cj0 + wc * 64 + lr;

  bf16x8 ah[4][2], al[4][2];
#pragma unroll
  for (int rb = 0; rb < 4; ++rb)
#pragma unroll
    for (int ks = 0; ks < 2; ++ks) {
      int o = (arow + rb * 16) * 64 + ks * 32 + lk;
      ah[rb][ks] = *(const bf16x8*)(zh + o);
      al[rb][ks] = *(const bf16x8*)(zl + o);
    }
  int orow = ri0 + wr * 64 + ((lane >> 4) << 2);
  int ocol = cj0 + wc * 64 + (lane & 15);
#pragma unroll
  for (int cb = 0; cb < 4; ++cb) {
    bf16x8 bh[2], bl[2];
#pragma unroll
    for (int ks = 0; ks < 2; ++ks) {
      int o = (brow + cb * 16) * 64 + ks * 32 + lk;
      bh[ks] = *(const bf16x8*)(zh + o);
      bl[ks] = *(const bf16x8*)(zl + o);
    }
    f32x4 acc[4] = {};
#pragma unroll
    for (int rb = 0; rb < 4; ++rb) {
      f32x4 c = acc[rb];
#pragma unroll
      for (int ks = 0; ks < 2; ++ks) {
        c = __builtin_amdgcn_mfma_f32_16x16x32_bf16(ah[rb][ks], bh[ks], c, 0, 0, 0);
        c = __builtin_amdgcn_mfma_f32_16x16x32_bf16(ah[rb][ks], bl[ks], c, 0, 0, 0);
        c = __builtin_amdgcn_mfma_f32_16x16x32_bf16(al[rb][ks], bh[ks], c, 0, 0, 0);
      }
      acc[rb] = c;
    }
#pragma unroll
    for (int rb = 0; rb < 4; ++rb)
#pragma unroll
      for (int r = 0; r < 4; ++r) {
        int row = orow + rb * 16 + r;
        int col = ocol + cb * 16;
        float v = acc[rb][r];
        float sg = 1.0f / (1.0f + __expf(-v));
        out[(size_t)row * NN + col] = (col > row) ? sg : 0.0f;
      }
  }
}

extern "C" void kernel_launch(void* const* d_in, const int* in_sizes, int n_in,
                              void* d_out, int out_size, void* d_ws, size_t ws_size,
                              hipStream_t stream) {
  (void)in_sizes; (void)n_in; (void)out_size; (void)ws_size;
  const float* x     = (const float*)d_in[0];
  const int*   ei    = (const int*)d_in[1];
  const float* ew    = (const float*)d_in[2];
  const float* noise = (const float*)d_in[3];
  const float* W1    = (const float*)d_in[4];
  const float* b1    = (const float*)d_in[5];
  const float* W2    = (const float*)d_in[6];
  const float* b2    = (const float*)d_in[7];
  const float* Wm    = (const float*)d_in[8];
  const float* bm    = (const float*)d_in[9];
  const float* Wsw   = (const float*)d_in[10];
  const float* bsv   = (const float*)d_in[11];
  float* out = (float*)d_out;

  char* wsb = (char*)d_ws;
  size_t off = 0;
  auto bump = [&](size_t bytes) -> void* {
    void* p = wsb + off;
    off += (bytes + 255) & ~(size_t)255;
    return p;
  };
  float* deg     = (float*)bump((size_t)NN * 4);
  int*   counts  = (int*)bump((size_t)NN * 4);
  int*   offs    = (int*)bump((size_t)(NN + 1) * 4);
  int*   cnt2    = (int*)bump((size_t)NN * 4);
  int*   csr_row = (int*)bump((size_t)NE * 4);
  float* csr_val = (float*)bump((size_t)NE * 4);
  __hip_bfloat16* xh = (__hip_bfloat16*)bump((size_t)NN * 512 * 2);
  __hip_bfloat16* xl = (__hip_bfloat16*)bump((size_t)NN * 512 * 2);
  float* bufA    = (float*)bump((size_t)NN * 256 * 4);
  __hip_bfloat16* h1h = (__hip_bfloat16*)bump((size_t)NN * 256 * 2);
  __hip_bfloat16* h1l = (__hip_bfloat16*)bump((size_t)NN * 256 * 2);
  __hip_bfloat16* W1hT = (__hip_bfloat16*)bump((size_t)256 * 512 * 2);
  __hip_bfloat16* W1lT = (__hip_bfloat16*)bump((size_t)256 * 512 * 2);
  __hip_bfloat16* W2hT = (__hip_bfloat16*)bump((size_t)256 * 256 * 2);
  __hip_bfloat16* W2lT = (__hip_bfloat16*)bump((size_t)256 * 256 * 2);
  __hip_bfloat16* WchT = (__hip_bfloat16*)bump((size_t)128 * 256 * 2);
  __hip_bfloat16* WclT = (__hip_bfloat16*)bump((size_t)128 * 256 * 2);
  float* bcat    = (float*)bump((size_t)128 * 4);
  __hip_bfloat16* zh = (__hip_bfloat16*)bump((size_t)NN * 64 * 2);
  __hip_bfloat16* zl = (__hip_bfloat16*)bump((size_t)NN * 64 * 2);

  __hip_bfloat16* h2h = xh;                 // alias: x pair dead after GEMM1
  __hip_bfloat16* h2l = xl;

  // CSR build + splits
  k_splitX<<<NN * 512 / 4 / 256, 256, 0, stream>>>(x, xh, xl, deg, counts, cnt2);
  k_count<<<NE / 256, 256, 0, stream>>>(ei, ew, deg, counts);
  k_scan<<<1, 1024, 0, stream>>>(counts, offs);
  k_scatter<<<NE / 256, 256, 0, stream>>>(ei, ew, deg, offs, cnt2, csr_row, csr_val);
  k_prep<<<896, 256, 0, stream>>>(W1, W2, Wm, Wsw, bm, bsv, W1hT, W1lT, W2hT, W2lT, WchT, WclT, bcat);

  // layer 1
  k_gemm_mfma<512, 256><<<2048, 256, 0, stream>>>((const short*)xh, (const short*)xl,
                                                  (const short*)W1hT, (const short*)W1lT, bufA);
  k_agg<256, true, 0><<<NN, 256, 0, stream>>>(bufA, deg, csr_row, csr_val, offs, b1, nullptr, h1h, h1l);
  // layer 2
  k_gemm_mfma<256, 256><<<2048, 256, 0, stream>>>((const short*)h1h, (const short*)h1l,
                                                  (const short*)W2hT, (const short*)W2lT, bufA);
  k_agg<256, true, 0><<<NN, 256, 0, stream>>>(bufA, deg, csr_row, csr_val, offs, b2, nullptr, h2h, h2l);
  // heads + fused z
  k_gemm_mfma<256, 128><<<1024, 256, 0, stream>>>((const short*)h2h, (const short*)h2l,
                                                  (const short*)WchT, (const short*)WclT, bufA);
  k_agg<128, false, 1><<<NN, 256, 0, stream>>>(bufA, deg, csr_row, csr_val, offs, bcat, noise, zh, zl);
  // final
  k_final<<<dim3(64, 64), 256, 0, stream>>>((const short*)zh, (const short*)zl, out);
}

// Round 10
// 277.507 us; speedup vs baseline: 2.4979x; 1.1610x over previous
//
#include <hip/hip_runtime.h>
#include <hip/hip_bf16.h>

#define NN 8192
#define NE 262144

typedef __attribute__((ext_vector_type(8))) short bf16x8;
typedef __attribute__((ext_vector_type(4))) float f32x4;

// ---------------- CSR build ----------------
__global__ __launch_bounds__(256) void k_count(const int* __restrict__ ei, const float* __restrict__ w,
                                               float* __restrict__ deg, int* __restrict__ counts) {
  int e = blockIdx.x * 256 + threadIdx.x;
  if (e < NE) {
    int c = ei[NE + e];
    atomicAdd(&deg[c], w[e]);
    atomicAdd(&counts[c], 1);
  }
}

__global__ __launch_bounds__(1024) void k_scan(const int* __restrict__ counts, int* __restrict__ offs) {
  __shared__ int part[1024];
  int t = threadIdx.x;
  int base = t * 8;
  int local[8];
  int s = 0;
#pragma unroll
  for (int j = 0; j < 8; ++j) { local[j] = counts[base + j]; s += local[j]; }
  part[t] = s;
  __syncthreads();
  for (int off = 1; off < 1024; off <<= 1) {
    int v = (t >= off) ? part[t - off] : 0;
    __syncthreads();
    part[t] += v;
    __syncthreads();
  }
  int run = (t > 0) ? part[t - 1] : 0;
#pragma unroll
  for (int j = 0; j < 8; ++j) { offs[base + j] = run; run += local[j]; }
  if (t == 1023) offs[NN] = run;
}

__global__ __launch_bounds__(256) void k_scatter(const int* __restrict__ ei, const float* __restrict__ w,
                                                 const float* __restrict__ deg, const int* __restrict__ offs,
                                                 int* __restrict__ cnt2, int* __restrict__ csr_row,
                                                 float* __restrict__ csr_val) {
  int e = blockIdx.x * 256 + threadIdx.x;
  if (e < NE) {
    int r = ei[e], c = ei[NE + e];
    int slot = offs[c] + atomicAdd(&cnt2[c], 1);
    csr_row[slot] = r;
    csr_val[slot] = rsqrtf(deg[r]) * w[e] * rsqrtf(deg[c]);
  }
}

// ---------------- split x + split/transpose all weights + CSR init (one kernel) ----------------
__global__ __launch_bounds__(256) void k_splitX(const float* __restrict__ x,
                                                __hip_bfloat16* __restrict__ xh,
                                                __hip_bfloat16* __restrict__ xl,
                                                float* __restrict__ deg, int* __restrict__ counts,
                                                int* __restrict__ cnt2,
                                                const float* __restrict__ W1, const float* __restrict__ W2,
                                                const float* __restrict__ Wm, const float* __restrict__ Wsw,
                                                const float* __restrict__ bm, const float* __restrict__ bsv,
                                                __hip_bfloat16* __restrict__ W1hT, __hip_bfloat16* __restrict__ W1lT,
                                                __hip_bfloat16* __restrict__ W2hT, __hip_bfloat16* __restrict__ W2lT,
                                                __hip_bfloat16* __restrict__ WchT, __hip_bfloat16* __restrict__ WclT,
                                                float* __restrict__ bcat) {
  int gtid = blockIdx.x * 256 + threadIdx.x;
  int gs = gridDim.x * 256;
  if (gtid < NN) { deg[gtid] = 1.0f; counts[gtid] = 0; cnt2[gtid] = 0; }
  size_t i = (size_t)gtid * 4;
  f32x4 v = *(const f32x4*)(x + i);
#pragma unroll
  for (int j = 0; j < 4; ++j) {
    __hip_bfloat16 h = __float2bfloat16(v[j]);
    xh[i + j] = h;
    xl[i + j] = __float2bfloat16(v[j] - __bfloat162float(h));
  }
  for (int idx = gtid; idx < 512 * 256; idx += gs) {
    int k = idx >> 8, n = idx & 255;
    float w = W1[idx];
    __hip_bfloat16 h = __float2bfloat16(w);
    W1hT[n * 512 + k] = h;
    W1lT[n * 512 + k] = __float2bfloat16(w - __bfloat162float(h));
  }
  for (int idx = gtid; idx < 256 * 256; idx += gs) {
    int k = idx >> 8, n = idx & 255;
    float w = W2[idx];
    __hip_bfloat16 h = __float2bfloat16(w);
    W2hT[n * 256 + k] = h;
    W2lT[n * 256 + k] = __float2bfloat16(w - __bfloat162float(h));
  }
  for (int idx = gtid; idx < 128 * 256; idx += gs) {
    int n = idx >> 8, k = idx & 255;
    float w = (n < 64) ? Wm[k * 64 + n] : Wsw[k * 64 + (n - 64)];
    __hip_bfloat16 h = __float2bfloat16(w);
    WchT[idx] = h;
    WclT[idx] = __float2bfloat16(w - __bfloat162float(h));
  }
  if (gtid < 128) bcat[gtid] = (gtid < 64) ? bm[gtid] : bsv[gtid - 64];
}

// ---------------- split-bf16 MFMA GEMM: 64x64 block, 2x2 frags/wave, XCD-aware mapping ----------------
// Linear grid b: by = b & 127 (fast), bx = b >> 7 (slow). XCD(b) = b%8 = by%8, so all
// NTX blocks sharing A-panel `by` run on the SAME XCD -> A-panel fetched once, L2-resident
// (16 panels x 128KB = 2MB/XCD). B-panels (<=128KB) trivially L2-resident.
template <int K, int Nc>
__global__ __launch_bounds__(256) void k_gemm_mfma(const short* __restrict__ Ah, const short* __restrict__ Al,
                                                   const short* __restrict__ BhT, const short* __restrict__ BlT,
                                                   float* __restrict__ C) {
  int b = blockIdx.x;
  int by = b & 127, bx = b >> 7;
  int m0 = by * 64, n0 = bx * 64;
  int wv = threadIdx.x >> 6, lane = threadIdx.x & 63;
  int wr = wv >> 1, wc = wv & 1;
  int lr = lane & 15, lk8 = (lane >> 4) << 3;
  int arow = m0 + wr * 32 + lr;
  int bcol = n0 + wc * 32 + lr;
  f32x4 acc[2][2] = {};
#pragma unroll 4
  for (int k0 = 0; k0 < K; k0 += 32) {
    bf16x8 ah[2], al[2], bh[2], bl[2];
#pragma unroll
    for (int rb = 0; rb < 2; ++rb) {
      size_t o = (size_t)(arow + rb * 16) * K + k0 + lk8;
      ah[rb] = *(const bf16x8*)(Ah + o);
      al[rb] = *(const bf16x8*)(Al + o);
    }
#pragma unroll
    for (int cb = 0; cb < 2; ++cb) {
      size_t o = (size_t)(bcol + cb * 16) * K + k0 + lk8;
      bh[cb] = *(const bf16x8*)(BhT + o);
      bl[cb] = *(const bf16x8*)(BlT + o);
    }
#pragma unroll
    for (int rb = 0; rb < 2; ++rb)
#pragma unroll
      for (int cb = 0; cb < 2; ++cb) {
        f32x4 c = acc[rb][cb];
        c = __builtin_amdgcn_mfma_f32_16x16x32_bf16(ah[rb], bh[cb], c, 0, 0, 0);
        c = __builtin_amdgcn_mfma_f32_16x16x32_bf16(ah[rb], bl[cb], c, 0, 0, 0);
        c = __builtin_amdgcn_mfma_f32_16x16x32_bf16(al[rb], bh[cb], c, 0, 0, 0);
        acc[rb][cb] = c;
      }
  }
  int orow = m0 + wr * 32 + ((lane >> 4) << 2);
  int ocol = n0 + wc * 32 + (lane & 15);
#pragma unroll
  for (int rb = 0; rb < 2; ++rb)
#pragma unroll
    for (int cb = 0; cb < 2; ++cb)
#pragma unroll
      for (int r = 0; r < 4; ++r)
        C[(size_t)(orow + rb * 16 + r) * Nc + ocol + cb * 16] = acc[rb][cb][r];
}

// ---------------- CSR aggregation; ZMODE=1 fuses reparameterized z (D=128 only) ----------------
template <int D, bool SPLIT, int ZMODE>
__global__ __launch_bounds__(256) void k_agg(const float* __restrict__ t, const float* __restrict__ deg,
                                             const int* __restrict__ csr_row, const float* __restrict__ csr_val,
                                             const int* __restrict__ offs, const float* __restrict__ bias,
                                             const float* __restrict__ noise,
                                             __hip_bfloat16* __restrict__ outh,
                                             __hip_bfloat16* __restrict__ outl) {
  constexpr int V = D / 64;
  __shared__ int   srow[256];
  __shared__ float sval[256];
  __shared__ float sacc[4][D];
  int c = blockIdx.x;
  int tid = threadIdx.x;
  int w = tid >> 6, lane = tid & 63;
  int d0 = lane * V;
  float acc[V];
#pragma unroll
  for (int j = 0; j < V; ++j) acc[j] = 0.0f;
  int s0 = offs[c], s1 = offs[c + 1];
  for (int base = s0; base < s1; base += 256) {
    int cnt = s1 - base; if (cnt > 256) cnt = 256;
    __syncthreads();
    if (tid < cnt) { srow[tid] = csr_row[base + tid]; sval[tid] = csr_val[base + tid]; }
    __syncthreads();
    for (int s = w; s < cnt; s += 4) {
      int r = srow[s];
      float v = sval[s];
      const float* q = t + (size_t)r * D + d0;
      if constexpr (V == 4) {
        float4 pv = *(const float4*)q;
        acc[0] = fmaf(v, pv.x, acc[0]);
        acc[1] = fmaf(v, pv.y, acc[1]);
        acc[2] = fmaf(v, pv.z, acc[2]);
        acc[3] = fmaf(v, pv.w, acc[3]);
      } else {
        float2 pv = *(const float2*)q;
        acc[0] = fmaf(v, pv.x, acc[0]);
        acc[1] = fmaf(v, pv.y, acc[1]);
      }
    }
  }
#pragma unroll
  for (int j = 0; j < V; ++j) sacc[w][d0 + j] = acc[j];
  __syncthreads();
  if (tid < 64) {
    float di = rsqrtf(deg[c]);
    float selfw = di * di;
#pragma unroll
    for (int j = 0; j < V; ++j) {
      int d = tid * V + j;
      float a = sacc[0][d] + sacc[1][d] + sacc[2][d] + sacc[3][d];
      a = fmaf(selfw, t[(size_t)c * D + d], a);
      a = fmaxf(a + bias[d], 0.0f);
      if constexpr (ZMODE == 0) {
        __hip_bfloat16 h = __float2bfloat16(a);
        outh[(size_t)c * D + d] = h;
        outl[(size_t)c * D + d] = __float2bfloat16(a - __bfloat162float(h));
      } else {
        sacc[0][d] = a;    // own d only: no cross-thread hazard before sync
      }
    }
  }
  if constexpr (ZMODE == 1) {
    __syncthreads();
    if (tid < 64) {
      float mean = sacc[0][tid];
      float ls = sacc[0][64 + tid];
      float z = noise[(size_t)c * 64 + tid] * __expf(ls) + mean;
      __hip_bfloat16 h = __float2bfloat16(z);
      outh[(size_t)c * 64 + tid] = h;
      outl[(size_t)c * 64 + tid] = __float2bfloat16(z - __bfloat162float(h));
    }
  }
}

// ---------------- final: triu(sigmoid(z z^T), 1), split-bf16 MFMA ----------------
__global__ __launch_bounds__(256) void k_final(const short* __restrict__ zh, const short* __restrict__ zl,
                                               float* __restrict__ out) {
  int ti = blockIdx.y, tj = blockIdx.x;
  int ri0 = ti * 128, cj0 = tj * 128;
  if (tj < ti) {
    f32x4 zz = {};
    int tr = threadIdx.x >> 5;
    int tc = (threadIdx.x & 31) << 2;
    float* base = out + (size_t)(ri0 + tr) * NN + cj0 + tc;
#pragma unroll
    for (int rr = 0; rr < 128; rr += 8)
      *(f32x4*)(base + (size_t)rr * NN) = zz;
    return;
  }
  int wv = threadIdx.x >> 6;
  int lane = threadIdx.x & 63;
  int wr = wv >> 1, wc = wv & 1;
  int lr = lane & 15;
  int lk = (lane >> 4) << 3;
  int arow = ri0 + wr * 64 + lr;
  int brow = cj0 + wc * 64 + lr;

  bf16x8 ah[4][2], al[4][2];
#pragma unroll
  for (int rb = 0; rb < 4; ++rb)
#pragma unroll
    for (int ks = 0; ks < 2; ++ks) {
      int o = (arow + rb * 16) * 64 + ks * 32 + lk;
      ah[rb][ks] = *(const bf16x8*)(zh + o);
      al[rb][ks] = *(const bf16x8*)(zl + o);
    }
  int orow = ri0 + wr * 64 + ((lane >> 4) << 2);
  int ocol = cj0 + wc * 64 + (lane & 15);
#pragma unroll
  for (int cb = 0; cb < 4; ++cb) {
    bf16x8 bh[2], bl[2];
#pragma unroll
    for (int ks = 0; ks < 2; ++ks) {
      int o = (brow + cb * 16) * 64 + ks * 32 + lk;
      bh[ks] = *(const bf16x8*)(zh + o);
      bl[ks] = *(const bf16x8*)(zl + o);
    }
    f32x4 acc[4] = {};
#pragma unroll
    for (int rb = 0; rb < 4; ++rb) {
      f32x4 c = acc[rb];
#pragma unroll
      for (int ks = 0; ks < 2; ++ks) {
        c = __builtin_amdgcn_mfma_f32_16x16x32_bf16(ah[rb][ks], bh[ks], c, 0, 0, 0);
        c = __builtin_amdgcn_mfma_f32_16x16x32_bf16(ah[rb][ks], bl[ks], c, 0, 0, 0);
        c = __builtin_amdgcn_mfma_f32_16x16x32_bf16(al[rb][ks], bh[ks], c, 0, 0, 0);
      }
      acc[rb] = c;
    }
#pragma unroll
    for (int rb = 0; rb < 4; ++rb)
#pragma unroll
      for (int r = 0; r < 4; ++r) {
        int row = orow + rb * 16 + r;
        int col = ocol + cb * 16;
        float v = acc[rb][r];
        float sg = 1.0f / (1.0f + __expf(-v));
        out[(size_t)row * NN + col] = (col > row) ? sg : 0.0f;
      }
  }
}

extern "C" void kernel_launch(void* const* d_in, const int* in_sizes, int n_in,
                              void* d_out, int out_size, void* d_ws, size_t ws_size,
                              hipStream_t stream) {
  (void)in_sizes; (void)n_in; (void)out_size; (void)ws_size;
  const float* x     = (const float*)d_in[0];
  const int*   ei    = (const int*)d_in[1];
  const float* ew    = (const float*)d_in[2];
  const float* noise = (const float*)d_in[3];
  const float* W1    = (const float*)d_in[4];
  const float* b1    = (const float*)d_in[5];
  const float* W2    = (const float*)d_in[6];
  const float* b2    = (const float*)d_in[7];
  const float* Wm    = (const float*)d_in[8];
  const float* bm    = (const float*)d_in[9];
  const float* Wsw   = (const float*)d_in[10];
  const float* bsv   = (const float*)d_in[11];
  float* out = (float*)d_out;

  char* wsb = (char*)d_ws;
  size_t off = 0;
  auto bump = [&](size_t bytes) -> void* {
    void* p = wsb + off;
    off += (bytes + 255) & ~(size_t)255;
    return p;
  };
  float* deg     = (float*)bump((size_t)NN * 4);
  int*   counts  = (int*)bump((size_t)NN * 4);
  int*   offs    = (int*)bump((size_t)(NN + 1) * 4);
  int*   cnt2    = (int*)bump((size_t)NN * 4);
  int*   csr_row = (int*)bump((size_t)NE * 4);
  float* csr_val = (float*)bump((size_t)NE * 4);
  __hip_bfloat16* xh = (__hip_bfloat16*)bump((size_t)NN * 512 * 2);
  __hip_bfloat16* xl = (__hip_bfloat16*)bump((size_t)NN * 512 * 2);
  float* bufA    = (float*)bump((size_t)NN * 256 * 4);
  __hip_bfloat16* h1h = (__hip_bfloat16*)bump((size_t)NN * 256 * 2);
  __hip_bfloat16* h1l = (__hip_bfloat16*)bump((size_t)NN * 256 * 2);
  __hip_bfloat16* W1hT = (__hip_bfloat16*)bump((size_t)256 * 512 * 2);
  __hip_bfloat16* W1lT = (__hip_bfloat16*)bump((size_t)256 * 512 * 2);
  __hip_bfloat16* W2hT = (__hip_bfloat16*)bump((size_t)256 * 256 * 2);
  __hip_bfloat16* W2lT = (__hip_bfloat16*)bump((size_t)256 * 256 * 2);
  __hip_bfloat16* WchT = (__hip_bfloat16*)bump((size_t)128 * 256 * 2);
  __hip_bfloat16* WclT = (__hip_bfloat16*)bump((size_t)128 * 256 * 2);
  float* bcat    = (float*)bump((size_t)128 * 4);
  __hip_bfloat16* zh = (__hip_bfloat16*)bump((size_t)NN * 64 * 2);
  __hip_bfloat16* zl = (__hip_bfloat16*)bump((size_t)NN * 64 * 2);

  __hip_bfloat16* h2h = xh;                 // alias: x pair dead after GEMM1
  __hip_bfloat16* h2l = xl;

  // CSR build + splits (one prep kernel)
  k_splitX<<<NN * 512 / 4 / 256, 256, 0, stream>>>(x, xh, xl, deg, counts, cnt2,
                                                   W1, W2, Wm, Wsw, bm, bsv,
                                                   W1hT, W1lT, W2hT, W2lT, WchT, WclT, bcat);
  k_count<<<NE / 256, 256, 0, stream>>>(ei, ew, deg, counts);
  k_scan<<<1, 1024, 0, stream>>>(counts, offs);
  k_scatter<<<NE / 256, 256, 0, stream>>>(ei, ew, deg, offs, cnt2, csr_row, csr_val);

  // layer 1
  k_gemm_mfma<512, 256><<<512, 256, 0, stream>>>((const short*)xh, (const short*)xl,
                                                 (const short*)W1hT, (const short*)W1lT, bufA);
  k_agg<256, true, 0><<<NN, 256, 0, stream>>>(bufA, deg, csr_row, csr_val, offs, b1, nullptr, h1h, h1l);
  // layer 2
  k_gemm_mfma<256, 256><<<512, 256, 0, stream>>>((const short*)h1h, (const short*)h1l,
                                                 (const short*)W2hT, (const short*)W2lT, bufA);
  k_agg<256, true, 0><<<NN, 256, 0, stream>>>(bufA, deg, csr_row, csr_val, offs, b2, nullptr, h2h, h2l);
  // heads + fused z
  k_gemm_mfma<256, 128><<<256, 256, 0, stream>>>((const short*)h2h, (const short*)h2l,
                                                 (const short*)WchT, (const short*)WclT, bufA);
  k_agg<128, false, 1><<<NN, 256, 0, stream>>>(bufA, deg, csr_row, csr_val, offs, bcat, noise, zh, zl);
  // final
  k_final<<<dim3(64, 64), 256, 0, stream>>>((const short*)zh, (const short*)zl, out);
}